// Round 6
// baseline (900.598 us; speedup 1.0000x reference)
//
#include <hip/hip_runtime.h>
#include <hip/hip_cooperative_groups.h>

namespace cg = cooperative_groups;

#define NN 50000
#define NE 640000
#define NB 196        // (NN+255)/256
#define NSTRIP 3125   // NN/16
#define FDIM 128
#define FOUT 40

typedef unsigned int uint;
typedef unsigned short ushort;
typedef __attribute__((ext_vector_type(8))) __bf16 bf16x8;
typedef __attribute__((ext_vector_type(4))) float f32x4;

union BF8 { bf16x8 v; uint4 u; ushort s[8]; };

__device__ __forceinline__ ushort f2bf(float f){
  uint b = __float_as_uint(f);
  b += 0x7fffu + ((b >> 16) & 1u);   // RNE; inputs never NaN/Inf here
  return (ushort)(b >> 16);
}
__device__ __forceinline__ float bflo(uint v){ return __uint_as_float(v << 16); }
__device__ __forceinline__ float bfhi(uint v){ return __uint_as_float(v & 0xffff0000u); }
__device__ __forceinline__ int get_edge(const void* ep, int is64, int idx){
  return is64 ? (int)(((const long long*)ep)[idx]) : ((const int*)ep)[idx];
}

// ================= phase functions (shared by mega-kernel and fallback) ======

__device__ __forceinline__ void ph_zero_detect(const unsigned long long* __restrict__ e64,
                                               int* __restrict__ flag, int* __restrict__ deg){
  int tid = blockIdx.x * blockDim.x + threadIdx.x;
  int gsz = gridDim.x * blockDim.x;
  for(int i = tid; i < NN; i += gsz) deg[i] = 0;
  if(blockIdx.x == 0 && threadIdx.x < 64){
    unsigned long long v = e64[threadIdx.x];
    int ok = (int)__all(v < 4294967296ULL);  // all-small => genuinely int64 data
    if(threadIdx.x == 0) *flag = ok;
  }
}

__device__ __forceinline__ void ph_count(const void* __restrict__ edges, int is64,
                                         int* __restrict__ deg){
  int tid = blockIdx.x * blockDim.x + threadIdx.x;
  int gsz = gridDim.x * blockDim.x;
  for(int e = tid; e < NE; e += gsz)
    atomicAdd(&deg[get_edge(edges, is64, NE + e)], 1);
}

__device__ __forceinline__ void ph_scan1(const int* __restrict__ deg, int* __restrict__ rp,
                                         int* __restrict__ bsum){
  __shared__ int s[256];
  for(int c = blockIdx.x; c < NB; c += gridDim.x){
    int t = threadIdx.x, i = c * 256 + t;
    int v = (i < NN) ? deg[i] : 0;
    s[t] = v; __syncthreads();
    for(int o = 1; o < 256; o <<= 1){
      int a = (t >= o) ? s[t - o] : 0;
      __syncthreads(); s[t] += a; __syncthreads();
    }
    if(i < NN) rp[i] = s[t] - v;
    if(t == 255) bsum[c] = s[255];
    __syncthreads();
  }
}

__device__ __forceinline__ void ph_scan2(int* __restrict__ bsum){
  if(blockIdx.x == 0){
    __shared__ int s[256];
    int t = threadIdx.x;
    int v = (t < NB) ? bsum[t] : 0;
    s[t] = v; __syncthreads();
    for(int o = 1; o < 256; o <<= 1){
      int a = (t >= o) ? s[t - o] : 0;
      __syncthreads(); s[t] += a; __syncthreads();
    }
    if(t < NB) bsum[t] = s[t] - v;
  }
}

__device__ __forceinline__ void ph_scan3(int* __restrict__ rp, const int* __restrict__ bsum,
                                         int* __restrict__ cur){
  int tid = blockIdx.x * blockDim.x + threadIdx.x;
  int gsz = gridDim.x * blockDim.x;
  for(int i = tid; i < NN; i += gsz){ rp[i] += bsum[i >> 8]; cur[i] = 0; }
  if(tid == 0) rp[NN] = NE;
}

__device__ __forceinline__ void ph_fill(const void* __restrict__ edges, int is64,
                                        const int* __restrict__ rp, int* __restrict__ cur,
                                        int* __restrict__ col){
  int tid = blockIdx.x * blockDim.x + threadIdx.x;
  int gsz = gridDim.x * blockDim.x;
  for(int e = tid; e < NE; e += gsz){
    int d = get_edge(edges, is64, NE + e);
    int sdx = get_edge(edges, is64, e);
    int p = rp[d] + atomicAdd(&cur[d], 1);
    col[p] = sdx;
  }
}

// u = in@Wl^T (bf16), v = in@Wr^T + b (bf16); wave g owns cols [32g,32g+32)
template<int F32>
__device__ __forceinline__ void ph_linuv(const float* __restrict__ inF,
                                         const ushort* __restrict__ inB,
                                         const float* __restrict__ Wl,
                                         const float* __restrict__ Wr,
                                         const float* __restrict__ bias,
                                         ushort* __restrict__ u, ushort* __restrict__ v){
  int g = threadIdx.x >> 6;
  int l = threadIdx.x & 63;
  int r16 = l & 15, q = l >> 4;

  BF8 bl[2][4], br[2][4];
#pragma unroll
  for(int tt = 0; tt < 2; ++tt){
    int colw = 32 * g + 16 * tt + r16;
    const float* pl = Wl + colw * FDIM + q * 8;
    const float* pr = Wr + colw * FDIM + q * 8;
#pragma unroll
    for(int ks = 0; ks < 4; ++ks){
      float4 x0 = *(const float4*)(pl + 32 * ks);
      float4 x1 = *(const float4*)(pl + 32 * ks + 4);
      BF8 t;
      t.s[0]=f2bf(x0.x); t.s[1]=f2bf(x0.y); t.s[2]=f2bf(x0.z); t.s[3]=f2bf(x0.w);
      t.s[4]=f2bf(x1.x); t.s[5]=f2bf(x1.y); t.s[6]=f2bf(x1.z); t.s[7]=f2bf(x1.w);
      bl[tt][ks] = t;
      float4 y0 = *(const float4*)(pr + 32 * ks);
      float4 y1 = *(const float4*)(pr + 32 * ks + 4);
      BF8 w;
      w.s[0]=f2bf(y0.x); w.s[1]=f2bf(y0.y); w.s[2]=f2bf(y0.z); w.s[3]=f2bf(y0.w);
      w.s[4]=f2bf(y1.x); w.s[5]=f2bf(y1.y); w.s[6]=f2bf(y1.z); w.s[7]=f2bf(y1.w);
      br[tt][ks] = w;
    }
  }
  float bv0 = bias[32 * g + r16];
  float bv1 = bias[32 * g + 16 + r16];

  for(int s = blockIdx.x; s < NSTRIP; s += gridDim.x){
    int m0 = s * 16;
    BF8 a[4];
    if(F32){
      const float* pf = inF + (size_t)(m0 + r16) * FDIM + q * 8;
#pragma unroll
      for(int ks = 0; ks < 4; ++ks){
        float4 x0 = *(const float4*)(pf + 32 * ks);
        float4 x1 = *(const float4*)(pf + 32 * ks + 4);
        BF8 t;
        t.s[0]=f2bf(x0.x); t.s[1]=f2bf(x0.y); t.s[2]=f2bf(x0.z); t.s[3]=f2bf(x0.w);
        t.s[4]=f2bf(x1.x); t.s[5]=f2bf(x1.y); t.s[6]=f2bf(x1.z); t.s[7]=f2bf(x1.w);
        a[ks] = t;
      }
    } else {
      const ushort* pb = inB + (size_t)(m0 + r16) * FDIM + q * 8;
#pragma unroll
      for(int ks = 0; ks < 4; ++ks) a[ks].u = *(const uint4*)(pb + 32 * ks);
    }
    f32x4 aU0 = {0,0,0,0}, aU1 = {0,0,0,0}, aV0 = {0,0,0,0}, aV1 = {0,0,0,0};
#pragma unroll
    for(int ks = 0; ks < 4; ++ks){
      aU0 = __builtin_amdgcn_mfma_f32_16x16x32_bf16(a[ks].v, bl[0][ks].v, aU0, 0, 0, 0);
      aV0 = __builtin_amdgcn_mfma_f32_16x16x32_bf16(a[ks].v, br[0][ks].v, aV0, 0, 0, 0);
      aU1 = __builtin_amdgcn_mfma_f32_16x16x32_bf16(a[ks].v, bl[1][ks].v, aU1, 0, 0, 0);
      aV1 = __builtin_amdgcn_mfma_f32_16x16x32_bf16(a[ks].v, br[1][ks].v, aV1, 0, 0, 0);
    }
#pragma unroll
    for(int r = 0; r < 4; ++r){
      size_t row = (size_t)(m0 + q * 4 + r);
      u[row * FDIM + 32 * g + r16]      = f2bf(aU0[r]);
      u[row * FDIM + 32 * g + 16 + r16] = f2bf(aU1[r]);
      v[row * FDIM + 32 * g + r16]      = f2bf(aV0[r] + bv0);
      v[row * FDIM + 32 * g + 16 + r16] = f2bf(aV1[r] + bv1);
    }
  }
}

// h = relu(mean-gather(u) + v); one wave per node, wave-stride
__device__ __forceinline__ void ph_aggv(const ushort* __restrict__ u, const ushort* __restrict__ v,
                                        const int* __restrict__ rp, const int* __restrict__ col,
                                        ushort* __restrict__ h){
  int wid = (blockIdx.x * blockDim.x + threadIdx.x) >> 6;
  int nw  = (gridDim.x * blockDim.x) >> 6;
  int l = threadIdx.x & 63;
  int c16 = l & 15, eg = l >> 4;
  const ushort* fbase = u + c16 * 8;

  for(int node = wid; node < NN; node += nw){
    int beg = rp[node], deg = rp[node + 1] - beg;
    float acc[8] = {0.f,0.f,0.f,0.f,0.f,0.f,0.f,0.f};
    for(int base = 0; base < deg; base += 64){
      int nchunk = min(deg - base, 64);
      int idx = col[beg + base + min(l, nchunk - 1)];
#pragma unroll 2
      for(int j = 0; j < nchunk; j += 4){
        int e = j + eg;
        int s = __shfl(idx, min(e, nchunk - 1));
        uint4 w = *(const uint4*)(fbase + (size_t)s * FDIM);
        if(e < nchunk){
          acc[0] += bflo(w.x); acc[1] += bfhi(w.x);
          acc[2] += bflo(w.y); acc[3] += bfhi(w.y);
          acc[4] += bflo(w.z); acc[5] += bfhi(w.z);
          acc[6] += bflo(w.w); acc[7] += bfhi(w.w);
        }
      }
    }
#pragma unroll
    for(int i = 0; i < 8; ++i){
      acc[i] += __shfl_xor(acc[i], 16);
      acc[i] += __shfl_xor(acc[i], 32);
    }
    if(eg == 0){
      float inv = 1.0f / (float)max(deg, 1);
      uint4 vv = *(const uint4*)(v + (size_t)node * FDIM + c16 * 8);
      float z0 = fmaxf(acc[0]*inv + bflo(vv.x), 0.f), z1 = fmaxf(acc[1]*inv + bfhi(vv.x), 0.f);
      float z2 = fmaxf(acc[2]*inv + bflo(vv.y), 0.f), z3 = fmaxf(acc[3]*inv + bfhi(vv.y), 0.f);
      float z4 = fmaxf(acc[4]*inv + bflo(vv.z), 0.f), z5 = fmaxf(acc[5]*inv + bfhi(vv.z), 0.f);
      float z6 = fmaxf(acc[6]*inv + bflo(vv.w), 0.f), z7 = fmaxf(acc[7]*inv + bfhi(vv.w), 0.f);
      uint4 o;
      o.x = (uint)f2bf(z0) | ((uint)f2bf(z1) << 16);
      o.y = (uint)f2bf(z2) | ((uint)f2bf(z3) << 16);
      o.z = (uint)f2bf(z4) | ((uint)f2bf(z5) << 16);
      o.w = (uint)f2bf(z6) | ((uint)f2bf(z7) << 16);
      *(uint4*)(h + (size_t)node * FDIM + c16 * 8) = o;
    }
  }
}

// u3 = h2@W3l^T, v3 = h2@W3r^T + b3 (bf16, 40 cols); waves 0..2 own 16-col slabs
__device__ __forceinline__ void ph_linuv40(const ushort* __restrict__ inB,
                                           const float* __restrict__ Wl,
                                           const float* __restrict__ Wr,
                                           const float* __restrict__ bias,
                                           ushort* __restrict__ u3, ushort* __restrict__ v3){
  int g = threadIdx.x >> 6;
  if(g >= 3) return;
  int l = threadIdx.x & 63;
  int r16 = l & 15, q = l >> 4;
  int colw = 16 * g + r16;
  bool vcol = colw < FOUT;

  BF8 bl[4], br[4];
#pragma unroll
  for(int ks = 0; ks < 4; ++ks){
    BF8 t, w;
    if(vcol){
      const float* pl = Wl + colw * FDIM + q * 8 + 32 * ks;
      const float* pr = Wr + colw * FDIM + q * 8 + 32 * ks;
      float4 x0 = ((const float4*)pl)[0], x1 = ((const float4*)pl)[1];
      t.s[0]=f2bf(x0.x); t.s[1]=f2bf(x0.y); t.s[2]=f2bf(x0.z); t.s[3]=f2bf(x0.w);
      t.s[4]=f2bf(x1.x); t.s[5]=f2bf(x1.y); t.s[6]=f2bf(x1.z); t.s[7]=f2bf(x1.w);
      float4 y0 = ((const float4*)pr)[0], y1 = ((const float4*)pr)[1];
      w.s[0]=f2bf(y0.x); w.s[1]=f2bf(y0.y); w.s[2]=f2bf(y0.z); w.s[3]=f2bf(y0.w);
      w.s[4]=f2bf(y1.x); w.s[5]=f2bf(y1.y); w.s[6]=f2bf(y1.z); w.s[7]=f2bf(y1.w);
    } else {
      t.u = make_uint4(0,0,0,0);
      w.u = make_uint4(0,0,0,0);
    }
    bl[ks] = t; br[ks] = w;
  }
  float bv = vcol ? bias[colw] : 0.f;

  for(int s = blockIdx.x; s < NSTRIP; s += gridDim.x){
    int m0 = s * 16;
    BF8 a[4];
    const ushort* pb = inB + (size_t)(m0 + r16) * FDIM + q * 8;
#pragma unroll
    for(int ks = 0; ks < 4; ++ks) a[ks].u = *(const uint4*)(pb + 32 * ks);
    f32x4 aU = {0,0,0,0}, aV = {0,0,0,0};
#pragma unroll
    for(int ks = 0; ks < 4; ++ks){
      aU = __builtin_amdgcn_mfma_f32_16x16x32_bf16(a[ks].v, bl[ks].v, aU, 0, 0, 0);
      aV = __builtin_amdgcn_mfma_f32_16x16x32_bf16(a[ks].v, br[ks].v, aV, 0, 0, 0);
    }
    if(vcol){
#pragma unroll
      for(int r = 0; r < 4; ++r){
        size_t row = (size_t)(m0 + q * 4 + r);
        u3[row * FOUT + colw] = f2bf(aU[r]);
        v3[row * FOUT + colw] = f2bf(aV[r] + bv);
      }
    }
  }
}

// out = log_softmax(mean-gather(u3) + v3); one wave per node, wave-stride
__device__ __forceinline__ void ph_agg40(const ushort* __restrict__ u3, const ushort* __restrict__ v3,
                                         const int* __restrict__ rp, const int* __restrict__ col,
                                         float* __restrict__ out){
  int wid = (blockIdx.x * blockDim.x + threadIdx.x) >> 6;
  int nw  = (gridDim.x * blockDim.x) >> 6;
  int l = threadIdx.x & 63;
  int c = l % 20, sl = l / 20;     // sl==3 -> idle for gather
  const ushort* fbase = u3 + 2 * c;

  for(int node = wid; node < NN; node += nw){
    int beg = rp[node], deg = rp[node + 1] - beg;
    float a0 = 0.f, a1 = 0.f;
    for(int base = 0; base < deg; base += 60){
      int nchunk = min(deg - base, 60);
      int idx = col[beg + base + min(l, nchunk - 1)];
#pragma unroll 2
      for(int j = 0; j < nchunk; j += 3){
        int e = j + sl;
        int s = __shfl(idx, min(e, nchunk - 1));
        uint w = *(const uint*)(fbase + (size_t)s * FOUT);
        if(sl < 3 && e < nchunk){
          a0 += bflo(w); a1 += bfhi(w);
        }
      }
    }
    a0 += __shfl(a0, l + 20) + __shfl(a0, l + 40);
    a1 += __shfl(a1, l + 20) + __shfl(a1, l + 40);

    float inv = 1.0f / (float)max(deg, 1);
    float z0 = 0.f, z1 = 0.f;
    if(l < 20){
      uint vv = *(const uint*)(v3 + (size_t)node * FOUT + 2 * c);
      z0 = a0 * inv + bflo(vv);
      z1 = a1 * inv + bfhi(vv);
    }
    float m = (l < 20) ? fmaxf(z0, z1) : -1e30f;
#pragma unroll
    for(int d = 1; d < 64; d <<= 1) m = fmaxf(m, __shfl_xor(m, d));
    float es = (l < 20) ? (__expf(z0 - m) + __expf(z1 - m)) : 0.f;
#pragma unroll
    for(int d = 1; d < 64; d <<= 1) es += __shfl_xor(es, d);
    float lse = m + __logf(es);
    if(l < 20){
      *(float2*)(out + (size_t)node * FOUT + 2 * c) = make_float2(z0 - lse, z1 - lse);
    }
  }
}

// ================= mega cooperative kernel ===================================

__launch_bounds__(256, 4)
__global__ void k_mega(const float* __restrict__ x, const void* __restrict__ edges,
                       int* __restrict__ flag, int* __restrict__ deg,
                       int* __restrict__ rp, int* __restrict__ col, int* __restrict__ bsum,
                       ushort* __restrict__ u, ushort* __restrict__ v,
                       ushort* __restrict__ h, ushort* __restrict__ h2,
                       const float* __restrict__ W1l, const float* __restrict__ b1, const float* __restrict__ W1r,
                       const float* __restrict__ W2l, const float* __restrict__ b2, const float* __restrict__ W2r,
                       const float* __restrict__ W3l, const float* __restrict__ b3, const float* __restrict__ W3r,
                       float* __restrict__ out){
  cg::grid_group grid = cg::this_grid();

  // phase 1: zero deg + dtype detect + layer-1 dense (x is independent of CSR)
  ph_zero_detect((const unsigned long long*)edges, flag, deg);
  ph_linuv<1>(x, nullptr, W1l, W1r, b1, u, v);
  grid.sync();
  int is64 = *flag;
  ph_count(edges, is64, deg);
  grid.sync();
  ph_scan1(deg, rp, bsum);
  grid.sync();
  ph_scan2(bsum);
  grid.sync();
  ph_scan3(rp, bsum, deg);       // deg becomes fill cursor
  grid.sync();
  ph_fill(edges, is64, rp, deg, col);
  grid.sync();
  ph_aggv(u, v, rp, col, h);
  grid.sync();
  ph_linuv<0>(nullptr, h, W2l, W2r, b2, u, v);
  grid.sync();
  ph_aggv(u, v, rp, col, h2);
  grid.sync();
  if((threadIdx.x >> 6) < 3) ph_linuv40(h2, W3l, W3r, b3, u, v);
  grid.sync();
  ph_agg40(u, v, rp, col, out);
}

// ================= fallback wrappers (12-kernel path) ========================

__global__ void k_f_zero_detect(const unsigned long long* e64, int* flag, int* deg){
  ph_zero_detect(e64, flag, deg);
}
__global__ void k_f_count(const void* edges, const int* flag, int* deg){
  ph_count(edges, *flag, deg);
}
__global__ void k_f_scan1(const int* deg, int* rp, int* bsum){ ph_scan1(deg, rp, bsum); }
__global__ void k_f_scan2(int* bsum){ ph_scan2(bsum); }
__global__ void k_f_scan3(int* rp, const int* bsum, int* cur){ ph_scan3(rp, bsum, cur); }
__global__ void k_f_fill(const void* edges, const int* flag, const int* rp, int* cur, int* col){
  ph_fill(edges, *flag, rp, cur, col);
}
__launch_bounds__(256)
__global__ void k_f_linuv1(const float* x, const float* Wl, const float* Wr,
                           const float* bias, ushort* u, ushort* v){
  ph_linuv<1>(x, nullptr, Wl, Wr, bias, u, v);
}
__launch_bounds__(256)
__global__ void k_f_linuv2(const ushort* inB, const float* Wl, const float* Wr,
                           const float* bias, ushort* u, ushort* v){
  ph_linuv<0>(nullptr, inB, Wl, Wr, bias, u, v);
}
__global__ void k_f_aggv(const ushort* u, const ushort* v, const int* rp, const int* col,
                         ushort* h){
  ph_aggv(u, v, rp, col, h);
}
__launch_bounds__(192)
__global__ void k_f_linuv40(const ushort* inB, const float* Wl, const float* Wr,
                            const float* bias, ushort* u3, ushort* v3){
  ph_linuv40(inB, Wl, Wr, bias, u3, v3);
}
__global__ void k_f_agg40(const ushort* u3, const ushort* v3, const int* rp, const int* col,
                          float* out){
  ph_agg40(u3, v3, rp, col, out);
}

// ================= host ======================================================

extern "C" void kernel_launch(void* const* d_in, const int* in_sizes, int n_in,
                              void* d_out, int out_size, void* d_ws, size_t ws_size,
                              hipStream_t stream){
  const float* x   = (const float*)d_in[0];
  const void*  edges = d_in[1];
  const float* W1l = (const float*)d_in[2];
  const float* b1  = (const float*)d_in[3];
  const float* W1r = (const float*)d_in[4];
  const float* W2l = (const float*)d_in[5];
  const float* b2  = (const float*)d_in[6];
  const float* W2r = (const float*)d_in[7];
  const float* W3l = (const float*)d_in[8];
  const float* b3  = (const float*)d_in[9];
  const float* W3r = (const float*)d_in[10];
  float* out = (float*)d_out;

  char* ws = (char*)d_ws;
  size_t off = 0;
  auto alloc = [&](size_t bytes)->void*{
    void* p = ws + off;
    off += (bytes + 255) & ~(size_t)255;
    return p;
  };
  ushort* u    = (ushort*)alloc((size_t)NN * FDIM * 2);  // layer u / u3
  ushort* v    = (ushort*)alloc((size_t)NN * FDIM * 2);  // layer v / v3
  ushort* h    = (ushort*)alloc((size_t)NN * FDIM * 2);  // h1
  ushort* h2   = (ushort*)alloc((size_t)NN * FDIM * 2);
  int*    deg  = (int*)alloc((size_t)NN * 4);            // reused as cursor
  int*    rp   = (int*)alloc((size_t)(NN + 1) * 4);
  int*    col  = (int*)alloc((size_t)NE * 4);
  int*    bsum = (int*)alloc(1024);
  int*    flag = (int*)alloc(256);

  // ---- try the single cooperative mega-kernel ----
  bool done = false;
  int occ = 0;
  if(hipOccupancyMaxActiveBlocksPerMultiprocessor(&occ, k_mega, 256, 0) == hipSuccess && occ > 0){
    int ncu = 0;
    if(hipDeviceGetAttribute(&ncu, hipDeviceAttributeMultiprocessorCount, 0) != hipSuccess || ncu <= 0)
      ncu = 256;
    int grid = occ * ncu;
    if(grid > 2048) grid = 2048;
    void* args[] = { (void*)&x, (void*)&edges, (void*)&flag, (void*)&deg, (void*)&rp,
                     (void*)&col, (void*)&bsum, (void*)&u, (void*)&v, (void*)&h, (void*)&h2,
                     (void*)&W1l, (void*)&b1, (void*)&W1r,
                     (void*)&W2l, (void*)&b2, (void*)&W2r,
                     (void*)&W3l, (void*)&b3, (void*)&W3r, (void*)&out };
    if(hipLaunchCooperativeKernel((const void*)k_mega, dim3(grid), dim3(256), args, 0, stream)
       == hipSuccess)
      done = true;
  }

  if(!done){
    // ---- fallback: 12-kernel chain (identical math) ----
    k_f_zero_detect<<<(NN + 255) / 256, 256, 0, stream>>>((const unsigned long long*)edges, flag, deg);
    k_f_count<<<(NE + 255) / 256, 256, 0, stream>>>(edges, flag, deg);
    k_f_scan1<<<NB, 256, 0, stream>>>(deg, rp, bsum);
    k_f_scan2<<<1, 256, 0, stream>>>(bsum);
    k_f_scan3<<<NB, 256, 0, stream>>>(rp, bsum, deg);
    k_f_fill<<<(NE + 255) / 256, 256, 0, stream>>>(edges, flag, rp, deg, col);

    int aggGrid = (NN * 64 + 255) / 256;
    k_f_linuv1<<<625, 256, 0, stream>>>(x, W1l, W1r, b1, u, v);
    k_f_aggv<<<aggGrid, 256, 0, stream>>>(u, v, rp, col, h);
    k_f_linuv2<<<625, 256, 0, stream>>>(h, W2l, W2r, b2, u, v);
    k_f_aggv<<<aggGrid, 256, 0, stream>>>(u, v, rp, col, h2);
    k_f_linuv40<<<625, 192, 0, stream>>>(h2, W3l, W3r, b3, u, v);
    k_f_agg40<<<aggGrid, 256, 0, stream>>>(u, v, rp, col, out);
  }
}

// Round 7
// 262.551 us; speedup vs baseline: 3.4302x; 3.4302x over previous
//
#include <hip/hip_runtime.h>

#define NN 50000
#define NE 640000
#define NBLK 196      // (NN+255)/256
#define FDIM 128
#define FOUT 40

typedef unsigned int uint;
typedef unsigned short ushort;
typedef __attribute__((ext_vector_type(8))) __bf16 bf16x8;
typedef __attribute__((ext_vector_type(4))) float f32x4;

union BF8 { bf16x8 v; uint4 u; ushort s[8]; };

__device__ __forceinline__ ushort f2bf(float f){
  uint b = __float_as_uint(f);
  b += 0x7fffu + ((b >> 16) & 1u);   // RNE; inputs never NaN/Inf here
  return (ushort)(b >> 16);
}
__device__ __forceinline__ float bflo(uint v){ return __uint_as_float(v << 16); }
__device__ __forceinline__ float bfhi(uint v){ return __uint_as_float(v & 0xffff0000u); }
__device__ __forceinline__ int get_edge(const void* ep, int is64, int idx){
  return is64 ? (int)(((const long long*)ep)[idx]) : ((const int*)ep)[idx];
}

// ===== K1: layer-1 dense (blocks 0..624) || zero deg/ts + detect + weight cvt =====
__launch_bounds__(256)
__global__ void k_pre(const float* __restrict__ x,
                      const float* __restrict__ W1l, const float* __restrict__ W1r,
                      const float* __restrict__ b1,
                      ushort* __restrict__ u, ushort* __restrict__ v,
                      const unsigned long long* __restrict__ e64,
                      int* __restrict__ flag, int* __restrict__ deg,
                      unsigned long long* __restrict__ ts,
                      const float* __restrict__ W2l, const float* __restrict__ W2r,
                      const float* __restrict__ W3l, const float* __restrict__ W3r,
                      ushort* __restrict__ wb2l, ushort* __restrict__ wb2r,
                      ushort* __restrict__ wb3l, ushort* __restrict__ wb3r){
  if(blockIdx.x >= 625){
    int b = blockIdx.x - 625;          // 0..195
    int t = threadIdx.x;
    int i = b * 256 + t;
    if(i < NN) deg[i] = 0;
    if(i < NBLK) ts[i] = 0ULL;
    if(i < 16384)      wb2l[i]         = f2bf(W2l[i]);
    else if(i < 32768) wb2r[i - 16384] = f2bf(W2r[i - 16384]);
    else if(i < 37888) wb3l[i - 32768] = f2bf(W3l[i - 32768]);
    else if(i < 43008) wb3r[i - 37888] = f2bf(W3r[i - 37888]);
    if(b == 0 && t < 64){
      unsigned long long vv = e64[t];
      int ok = (int)__all(vv < 4294967296ULL);  // all-small => genuinely int64
      if(t == 0) *flag = ok;
    }
    return;
  }
  // ---- layer-1 dense: u = x@W1l^T, v = x@W1r^T + b1 (weights f32 in regs) ----
  int g = threadIdx.x >> 6;
  int l = threadIdx.x & 63;
  int worker = blockIdx.x;
  int r16 = l & 15, q = l >> 4;

  BF8 bl[2][4], br[2][4];
#pragma unroll
  for(int tt = 0; tt < 2; ++tt){
    int colw = 32 * g + 16 * tt + r16;
    const float* pl = W1l + colw * FDIM + q * 8;
    const float* pr = W1r + colw * FDIM + q * 8;
#pragma unroll
    for(int ks = 0; ks < 4; ++ks){
      float4 x0 = *(const float4*)(pl + 32 * ks);
      float4 x1 = *(const float4*)(pl + 32 * ks + 4);
      BF8 t;
      t.s[0]=f2bf(x0.x); t.s[1]=f2bf(x0.y); t.s[2]=f2bf(x0.z); t.s[3]=f2bf(x0.w);
      t.s[4]=f2bf(x1.x); t.s[5]=f2bf(x1.y); t.s[6]=f2bf(x1.z); t.s[7]=f2bf(x1.w);
      bl[tt][ks] = t;
      float4 y0 = *(const float4*)(pr + 32 * ks);
      float4 y1 = *(const float4*)(pr + 32 * ks + 4);
      BF8 w;
      w.s[0]=f2bf(y0.x); w.s[1]=f2bf(y0.y); w.s[2]=f2bf(y0.z); w.s[3]=f2bf(y0.w);
      w.s[4]=f2bf(y1.x); w.s[5]=f2bf(y1.y); w.s[6]=f2bf(y1.z); w.s[7]=f2bf(y1.w);
      br[tt][ks] = w;
    }
  }
  float bv0 = b1[32 * g + r16];
  float bv1 = b1[32 * g + 16 + r16];

  for(int s = 0; s < 5; ++s){
    int m0 = (worker * 5 + s) * 16;
    BF8 a[4];
    const float* pf = x + (size_t)(m0 + r16) * FDIM + q * 8;
#pragma unroll
    for(int ks = 0; ks < 4; ++ks){
      float4 x0 = *(const float4*)(pf + 32 * ks);
      float4 x1 = *(const float4*)(pf + 32 * ks + 4);
      BF8 t;
      t.s[0]=f2bf(x0.x); t.s[1]=f2bf(x0.y); t.s[2]=f2bf(x0.z); t.s[3]=f2bf(x0.w);
      t.s[4]=f2bf(x1.x); t.s[5]=f2bf(x1.y); t.s[6]=f2bf(x1.z); t.s[7]=f2bf(x1.w);
      a[ks] = t;
    }
    f32x4 aU0 = {0,0,0,0}, aU1 = {0,0,0,0}, aV0 = {0,0,0,0}, aV1 = {0,0,0,0};
#pragma unroll
    for(int ks = 0; ks < 4; ++ks){
      aU0 = __builtin_amdgcn_mfma_f32_16x16x32_bf16(a[ks].v, bl[0][ks].v, aU0, 0, 0, 0);
      aV0 = __builtin_amdgcn_mfma_f32_16x16x32_bf16(a[ks].v, br[0][ks].v, aV0, 0, 0, 0);
      aU1 = __builtin_amdgcn_mfma_f32_16x16x32_bf16(a[ks].v, bl[1][ks].v, aU1, 0, 0, 0);
      aV1 = __builtin_amdgcn_mfma_f32_16x16x32_bf16(a[ks].v, br[1][ks].v, aV1, 0, 0, 0);
    }
#pragma unroll
    for(int r = 0; r < 4; ++r){
      size_t row = (size_t)(m0 + q * 4 + r);
      u[row * FDIM + 32 * g + r16]      = f2bf(aU0[r]);
      u[row * FDIM + 32 * g + 16 + r16] = f2bf(aU1[r]);
      v[row * FDIM + 32 * g + r16]      = f2bf(aV0[r] + bv0);
      v[row * FDIM + 32 * g + 16 + r16] = f2bf(aV1[r] + bv1);
    }
  }
}

// ===== K2: degree count =====
__global__ void k_count(const void* __restrict__ edges, const int* __restrict__ flag,
                        int* __restrict__ deg){
  int e = blockIdx.x * blockDim.x + threadIdx.x;
  if(e >= NE) return;
  int is64 = *flag;
  atomicAdd(&deg[get_edge(edges, is64, NE + e)], 1);
}

// ===== K3: single-pass exclusive scan (decoupled lookback), also zeros cur =====
__global__ void k_scan(const int* __restrict__ deg, int* __restrict__ rp,
                       int* __restrict__ cur, unsigned long long* __restrict__ ts){
  __shared__ int s[256];
  __shared__ int exc_s;
  int c = blockIdx.x, t = threadIdx.x;
  int i = c * 256 + t;
  int vdeg = (i < NN) ? deg[i] : 0;
  s[t] = vdeg; __syncthreads();
  for(int o = 1; o < 256; o <<= 1){
    int a = (t >= o) ? s[t - o] : 0;
    __syncthreads(); s[t] += a; __syncthreads();
  }
  int total = s[255];
  if(t == 0){
    if(c == 0){
      __hip_atomic_store(&ts[0], (2ULL << 32) | (uint)total,
                         __ATOMIC_RELEASE, __HIP_MEMORY_SCOPE_AGENT);
      exc_s = 0;
    } else {
      __hip_atomic_store(&ts[c], (1ULL << 32) | (uint)total,
                         __ATOMIC_RELEASE, __HIP_MEMORY_SCOPE_AGENT);
      int exc = 0;
      for(int j = c - 1; j >= 0; --j){
        unsigned long long st;
        do {
          st = __hip_atomic_load(&ts[j], __ATOMIC_ACQUIRE, __HIP_MEMORY_SCOPE_AGENT);
        } while((st >> 32) == 0ULL);
        exc += (int)(uint)st;
        if((st >> 32) == 2ULL) break;
      }
      __hip_atomic_store(&ts[c], (2ULL << 32) | (uint)(exc + total),
                         __ATOMIC_RELEASE, __HIP_MEMORY_SCOPE_AGENT);
      exc_s = exc;
    }
  }
  __syncthreads();
  int exc = exc_s;
  if(i < NN){ rp[i] = exc + s[t] - vdeg; cur[i] = 0; }
  if(c == NBLK - 1 && t == 255) rp[NN] = NE;
}

// ===== K4: CSR fill =====
__global__ void k_fill(const void* __restrict__ edges, const int* __restrict__ flag,
                       const int* __restrict__ rp, int* __restrict__ cur,
                       int* __restrict__ col){
  int e = blockIdx.x * blockDim.x + threadIdx.x;
  if(e >= NE) return;
  int is64 = *flag;
  int d = get_edge(edges, is64, NE + e);
  int sdx = get_edge(edges, is64, e);
  int p = rp[d] + atomicAdd(&cur[d], 1);
  col[p] = sdx;
}

// ===== K5: fused h=relu(mean(u)+v) [LDS] -> u2=h@Wl^T, v2=h@Wr^T+b =====
// 1024 thr = 16 waves; wave w gathers node n0+w; then wave w MFMAs col-tile (w&7)
// for u (w<8) or v (w>=8). LDS [16][136] (pad kills stride-256B bank conflict).
__launch_bounds__(1024)
__global__ void k_fused128(const ushort* __restrict__ u, const ushort* __restrict__ v,
                           const int* __restrict__ rp, const int* __restrict__ col,
                           const ushort* __restrict__ wbl, const ushort* __restrict__ wbr,
                           const float* __restrict__ bias,
                           ushort* __restrict__ uo, ushort* __restrict__ vo){
  __shared__ ushort hs[16][136];
  int w = threadIdx.x >> 6;
  int l = threadIdx.x & 63;
  int c16 = l & 15, eg = l >> 4;
  int n0 = blockIdx.x * 16;
  int node = n0 + w;

  // ---- phase A: gather ----
  int beg = rp[node], deg = rp[node + 1] - beg;
  float acc[8] = {0.f,0.f,0.f,0.f,0.f,0.f,0.f,0.f};
  const ushort* fbase = u + c16 * 8;
  for(int base = 0; base < deg; base += 64){
    int nchunk = min(deg - base, 64);
    int idx = col[beg + base + min(l, nchunk - 1)];
#pragma unroll 2
    for(int j = 0; j < nchunk; j += 4){
      int e = j + eg;
      int s = __shfl(idx, min(e, nchunk - 1));
      uint4 wv = *(const uint4*)(fbase + (size_t)s * FDIM);
      if(e < nchunk){
        acc[0] += bflo(wv.x); acc[1] += bfhi(wv.x);
        acc[2] += bflo(wv.y); acc[3] += bfhi(wv.y);
        acc[4] += bflo(wv.z); acc[5] += bfhi(wv.z);
        acc[6] += bflo(wv.w); acc[7] += bfhi(wv.w);
      }
    }
  }
#pragma unroll
  for(int i = 0; i < 8; ++i){
    acc[i] += __shfl_xor(acc[i], 16);
    acc[i] += __shfl_xor(acc[i], 32);
  }
  if(eg == 0){
    float inv = 1.0f / (float)max(deg, 1);
    uint4 vv = *(const uint4*)(v + (size_t)node * FDIM + c16 * 8);
    float z0 = fmaxf(acc[0]*inv + bflo(vv.x), 0.f), z1 = fmaxf(acc[1]*inv + bfhi(vv.x), 0.f);
    float z2 = fmaxf(acc[2]*inv + bflo(vv.y), 0.f), z3 = fmaxf(acc[3]*inv + bfhi(vv.y), 0.f);
    float z4 = fmaxf(acc[4]*inv + bflo(vv.z), 0.f), z5 = fmaxf(acc[5]*inv + bfhi(vv.z), 0.f);
    float z6 = fmaxf(acc[6]*inv + bflo(vv.w), 0.f), z7 = fmaxf(acc[7]*inv + bfhi(vv.w), 0.f);
    uint4 o;
    o.x = (uint)f2bf(z0) | ((uint)f2bf(z1) << 16);
    o.y = (uint)f2bf(z2) | ((uint)f2bf(z3) << 16);
    o.z = (uint)f2bf(z4) | ((uint)f2bf(z5) << 16);
    o.w = (uint)f2bf(z6) | ((uint)f2bf(z7) << 16);
    *(uint4*)(&hs[w][c16 * 8]) = o;
  }
  __syncthreads();

  // ---- phase B: dense ----
  int r16 = c16, q = eg;
  int tile = w & 7;
  bool isV = w >= 8;
  int colw = tile * 16 + r16;
  const ushort* wsrc = isV ? wbr : wbl;
  BF8 bfr[4], afr[4];
#pragma unroll
  for(int ks = 0; ks < 4; ++ks){
    bfr[ks].u = *(const uint4*)(wsrc + (size_t)colw * FDIM + q * 8 + 32 * ks);
    afr[ks].u = *(const uint4*)(&hs[r16][q * 8 + 32 * ks]);
  }
  f32x4 am = {0,0,0,0};
#pragma unroll
  for(int ks = 0; ks < 4; ++ks)
    am = __builtin_amdgcn_mfma_f32_16x16x32_bf16(afr[ks].v, bfr[ks].v, am, 0, 0, 0);
  float bv = isV ? bias[colw] : 0.f;
  ushort* dst = isV ? vo : uo;
#pragma unroll
  for(int r = 0; r < 4; ++r){
    int row = n0 + q * 4 + r;
    dst[(size_t)row * FDIM + colw] = f2bf(am[r] + bv);
  }
}

// ===== K6: fused h2=relu(mean(u2)+v2) [LDS] -> u3/v3 (40 cols) =====
__launch_bounds__(1024)
__global__ void k_fused40(const ushort* __restrict__ u, const ushort* __restrict__ v,
                          const int* __restrict__ rp, const int* __restrict__ col,
                          const ushort* __restrict__ wbl, const ushort* __restrict__ wbr,
                          const float* __restrict__ bias,
                          ushort* __restrict__ uo, ushort* __restrict__ vo){
  __shared__ ushort hs[16][136];
  int w = threadIdx.x >> 6;
  int l = threadIdx.x & 63;
  int c16 = l & 15, eg = l >> 4;
  int n0 = blockIdx.x * 16;
  int node = n0 + w;

  int beg = rp[node], deg = rp[node + 1] - beg;
  float acc[8] = {0.f,0.f,0.f,0.f,0.f,0.f,0.f,0.f};
  const ushort* fbase = u + c16 * 8;
  for(int base = 0; base < deg; base += 64){
    int nchunk = min(deg - base, 64);
    int idx = col[beg + base + min(l, nchunk - 1)];
#pragma unroll 2
    for(int j = 0; j < nchunk; j += 4){
      int e = j + eg;
      int s = __shfl(idx, min(e, nchunk - 1));
      uint4 wv = *(const uint4*)(fbase + (size_t)s * FDIM);
      if(e < nchunk){
        acc[0] += bflo(wv.x); acc[1] += bfhi(wv.x);
        acc[2] += bflo(wv.y); acc[3] += bfhi(wv.y);
        acc[4] += bflo(wv.z); acc[5] += bfhi(wv.z);
        acc[6] += bflo(wv.w); acc[7] += bfhi(wv.w);
      }
    }
  }
#pragma unroll
  for(int i = 0; i < 8; ++i){
    acc[i] += __shfl_xor(acc[i], 16);
    acc[i] += __shfl_xor(acc[i], 32);
  }
  if(eg == 0){
    float inv = 1.0f / (float)max(deg, 1);
    uint4 vv = *(const uint4*)(v + (size_t)node * FDIM + c16 * 8);
    float z0 = fmaxf(acc[0]*inv + bflo(vv.x), 0.f), z1 = fmaxf(acc[1]*inv + bfhi(vv.x), 0.f);
    float z2 = fmaxf(acc[2]*inv + bflo(vv.y), 0.f), z3 = fmaxf(acc[3]*inv + bfhi(vv.y), 0.f);
    float z4 = fmaxf(acc[4]*inv + bflo(vv.z), 0.f), z5 = fmaxf(acc[5]*inv + bfhi(vv.z), 0.f);
    float z6 = fmaxf(acc[6]*inv + bflo(vv.w), 0.f), z7 = fmaxf(acc[7]*inv + bfhi(vv.w), 0.f);
    uint4 o;
    o.x = (uint)f2bf(z0) | ((uint)f2bf(z1) << 16);
    o.y = (uint)f2bf(z2) | ((uint)f2bf(z3) << 16);
    o.z = (uint)f2bf(z4) | ((uint)f2bf(z5) << 16);
    o.w = (uint)f2bf(z6) | ((uint)f2bf(z7) << 16);
    *(uint4*)(&hs[w][c16 * 8]) = o;
  }
  __syncthreads();

  int r16 = c16, q = eg;
  int tile = w & 7;
  bool isV = w >= 8;
  if(tile >= 3) return;           // 3 col-tiles cover 48>=40 cols
  int colw = tile * 16 + r16;
  bool vcol = colw < FOUT;
  const ushort* wsrc = isV ? wbr : wbl;
  BF8 bfr[4], afr[4];
#pragma unroll
  for(int ks = 0; ks < 4; ++ks){
    if(vcol) bfr[ks].u = *(const uint4*)(wsrc + (size_t)colw * FDIM + q * 8 + 32 * ks);
    else     bfr[ks].u = make_uint4(0,0,0,0);
    afr[ks].u = *(const uint4*)(&hs[r16][q * 8 + 32 * ks]);
  }
  f32x4 am = {0,0,0,0};
#pragma unroll
  for(int ks = 0; ks < 4; ++ks)
    am = __builtin_amdgcn_mfma_f32_16x16x32_bf16(afr[ks].v, bfr[ks].v, am, 0, 0, 0);
  if(vcol){
    float bv = isV ? bias[colw] : 0.f;
    ushort* dst = isV ? vo : uo;
#pragma unroll
    for(int r = 0; r < 4; ++r){
      int row = n0 + q * 4 + r;
      dst[(size_t)row * FOUT + colw] = f2bf(am[r] + bv);
    }
  }
}

// ===== K7: out = log_softmax(mean-gather(u3) + v3) =====
__global__ void k_agg40(const ushort* __restrict__ u3, const ushort* __restrict__ v3,
                        const int* __restrict__ rp, const int* __restrict__ col,
                        float* __restrict__ out){
  int node = (blockIdx.x * blockDim.x + threadIdx.x) >> 6;
  if(node >= NN) return;
  int l = threadIdx.x & 63;
  int c = l % 20, sl = l / 20;
  const ushort* fbase = u3 + 2 * c;

  int beg = rp[node], deg = rp[node + 1] - beg;
  float a0 = 0.f, a1 = 0.f;
  for(int base = 0; base < deg; base += 60){
    int nchunk = min(deg - base, 60);
    int idx = col[beg + base + min(l, nchunk - 1)];
#pragma unroll 2
    for(int j = 0; j < nchunk; j += 3){
      int e = j + sl;
      int s = __shfl(idx, min(e, nchunk - 1));
      uint w = *(const uint*)(fbase + (size_t)s * FOUT);
      if(sl < 3 && e < nchunk){
        a0 += bflo(w); a1 += bfhi(w);
      }
    }
  }
  a0 += __shfl(a0, l + 20) + __shfl(a0, l + 40);
  a1 += __shfl(a1, l + 20) + __shfl(a1, l + 40);

  float inv = 1.0f / (float)max(deg, 1);
  float z0 = 0.f, z1 = 0.f;
  if(l < 20){
    uint vv = *(const uint*)(v3 + (size_t)node * FOUT + 2 * c);
    z0 = a0 * inv + bflo(vv);
    z1 = a1 * inv + bfhi(vv);
  }
  float m = (l < 20) ? fmaxf(z0, z1) : -1e30f;
#pragma unroll
  for(int d = 1; d < 64; d <<= 1) m = fmaxf(m, __shfl_xor(m, d));
  float es = (l < 20) ? (__expf(z0 - m) + __expf(z1 - m)) : 0.f;
#pragma unroll
  for(int d = 1; d < 64; d <<= 1) es += __shfl_xor(es, d);
  float lse = m + __logf(es);
  if(l < 20){
    *(float2*)(out + (size_t)node * FOUT + 2 * c) = make_float2(z0 - lse, z1 - lse);
  }
}

// ===== host =====
extern "C" void kernel_launch(void* const* d_in, const int* in_sizes, int n_in,
                              void* d_out, int out_size, void* d_ws, size_t ws_size,
                              hipStream_t stream){
  const float* x   = (const float*)d_in[0];
  const void*  edges = d_in[1];
  const float* W1l = (const float*)d_in[2];
  const float* b1  = (const float*)d_in[3];
  const float* W1r = (const float*)d_in[4];
  const float* W2l = (const float*)d_in[5];
  const float* b2  = (const float*)d_in[6];
  const float* W2r = (const float*)d_in[7];
  const float* W3l = (const float*)d_in[8];
  const float* b3  = (const float*)d_in[9];
  const float* W3r = (const float*)d_in[10];
  float* out = (float*)d_out;

  char* ws = (char*)d_ws;
  size_t off = 0;
  auto alloc = [&](size_t bytes)->void*{
    void* p = ws + off;
    off += (bytes + 255) & ~(size_t)255;
    return p;
  };
  ushort* u    = (ushort*)alloc((size_t)NN * FDIM * 2);   // layer-1 u; later u3
  ushort* v    = (ushort*)alloc((size_t)NN * FDIM * 2);   // layer-1 v; later v3
  ushort* u2   = (ushort*)alloc((size_t)NN * FDIM * 2);
  ushort* v2   = (ushort*)alloc((size_t)NN * FDIM * 2);
  int*    deg  = (int*)alloc((size_t)NN * 4);             // reused as fill cursor
  int*    rp   = (int*)alloc((size_t)(NN + 1) * 4);
  int*    col  = (int*)alloc((size_t)NE * 4);
  int*    flag = (int*)alloc(256);
  unsigned long long* ts = (unsigned long long*)alloc(NBLK * 8);
  ushort* wb2l = (ushort*)alloc(16384 * 2);
  ushort* wb2r = (ushort*)alloc(16384 * 2);
  ushort* wb3l = (ushort*)alloc(5120 * 2);
  ushort* wb3r = (ushort*)alloc(5120 * 2);

  k_pre<<<625 + NBLK, 256, 0, stream>>>(x, W1l, W1r, b1, u, v,
                                        (const unsigned long long*)edges, flag, deg, ts,
                                        W2l, W2r, W3l, W3r, wb2l, wb2r, wb3l, wb3r);
  k_count<<<(NE + 255) / 256, 256, 0, stream>>>(edges, flag, deg);
  k_scan<<<NBLK, 256, 0, stream>>>(deg, rp, deg /*cur alias ok: rewritten after read*/, ts);
  k_fill<<<(NE + 255) / 256, 256, 0, stream>>>(edges, flag, rp, deg, col);
  k_fused128<<<NN / 16, 1024, 0, stream>>>(u, v, rp, col, wb2l, wb2r, b2, u2, v2);
  k_fused40 <<<NN / 16, 1024, 0, stream>>>(u2, v2, rp, col, wb3l, wb3r, b3, u, v);
  k_agg40<<<(NN * 64 + 255) / 256, 256, 0, stream>>>(u, v, rp, col, out);
}